// Round 1
// baseline (1967.407 us; speedup 1.0000x reference)
//
#include <hip/hip_runtime.h>
#include <math.h>

#define BATCH   131072
#define IN_F    80
#define EMB     64
#define NE      16
#define RANK    8
#define UDIM    16
#define NCLS    10
#define NUSERS  1000
#define W2P     12   // padded e_w2 row (10 -> 12 floats for float4 alignment)

// ---- workspace layout (bytes) ----
#define OFF_H      0ull                       // BATCH*64 f32    = 33554432 B
#define OFF_TOPE   33554432ull                // 2*BATCH int     =  1048576 B
#define OFF_TOPW   34603008ull                // 2*BATCH f32     =  1048576 B
#define OFF_PAIRB  35651584ull                // 2*BATCH int     =  2097152 B
#define OFF_PAIRW  37748736ull                // 2*BATCH f32     =  2097152 B
#define OFF_UV     39845888ull                // 1000*16*8 f32   =   512000 B
#define OFF_HIST   40357888ull                // 16 int
#define OFF_OFFS   40358144ull                // 16 int
#define OFF_CUR    40358400ull                // 16 int

__device__ __forceinline__ float gelu_f(float v) {
    // exact GELU: x * 0.5 * (1 + erf(x/sqrt(2)))
    return 0.5f * v * (1.0f + erff(v * 0.70710678118654752440f));
}

// ---------------- uV[user][e][r] = sum_d ut[user][d] * gV[e][d][r] ----------------
__global__ void k_uv(const float* __restrict__ gV, const float* __restrict__ ut,
                     float* __restrict__ uv)
{
    int idx = blockIdx.x * 256 + threadIdx.x;
    if (idx >= NUSERS * NE) return;
    int u = idx / NE, e = idx - u * NE;
    const float* uvec = ut + u * UDIM;
    float acc[RANK];
#pragma unroll
    for (int r = 0; r < RANK; ++r) acc[r] = 0.0f;
#pragma unroll
    for (int d = 0; d < UDIM; ++d) {
        float ud = uvec[d];
        const float* gv = gV + (e * UDIM + d) * RANK;
#pragma unroll
        for (int r = 0; r < RANK; ++r) acc[r] = fmaf(ud, gv[r], acc[r]);
    }
    float* o = uv + (u * NE + e) * RANK;
#pragma unroll
    for (int r = 0; r < RANK; ++r) o[r] = acc[r];
}

// ---------------- backbone: fc1+gelu, fc2+gelu, LN -> h[B][64] ----------------
__global__ __launch_bounds__(256) void k_backbone(
    const float* __restrict__ x,
    const float* __restrict__ w1, const float* __restrict__ b1,
    const float* __restrict__ w2, const float* __restrict__ b2,
    const float* __restrict__ gam, const float* __restrict__ bet,
    float* __restrict__ h_out)
{
    __shared__ __align__(16) float s_w1[IN_F * EMB];
    __shared__ __align__(16) float s_w2[EMB * EMB];
    __shared__ __align__(16) float s_b1[EMB];
    __shared__ __align__(16) float s_b2[EMB];
    __shared__ __align__(16) float s_gam[EMB];
    __shared__ __align__(16) float s_bet[EMB];
    const int tid = threadIdx.x;
    for (int i = tid; i < IN_F * EMB; i += 256) s_w1[i] = w1[i];
    for (int i = tid; i < EMB * EMB; i += 256) s_w2[i] = w2[i];
    if (tid < EMB) { s_b1[tid] = b1[tid]; s_b2[tid] = b2[tid]; s_gam[tid] = gam[tid]; s_bet[tid] = bet[tid]; }
    __syncthreads();

    const int b = blockIdx.x * 256 + tid;

    float xf[IN_F];
    const float4* xp = (const float4*)(x + (size_t)b * IN_F);
#pragma unroll
    for (int t = 0; t < IN_F / 4; ++t) {
        float4 v = xp[t];
        xf[4*t+0] = v.x; xf[4*t+1] = v.y; xf[4*t+2] = v.z; xf[4*t+3] = v.w;
    }

    float h1[EMB];
    {
        const float4* sw = (const float4*)s_w1;
        const float4* sb = (const float4*)s_b1;
#pragma unroll
        for (int k0 = 0; k0 < EMB / 4; ++k0) {
            float4 a = sb[k0];
#pragma unroll
            for (int d = 0; d < IN_F; ++d) {
                float4 w = sw[d * (EMB / 4) + k0];
                a.x = fmaf(xf[d], w.x, a.x);
                a.y = fmaf(xf[d], w.y, a.y);
                a.z = fmaf(xf[d], w.z, a.z);
                a.w = fmaf(xf[d], w.w, a.w);
            }
            h1[4*k0+0] = gelu_f(a.x); h1[4*k0+1] = gelu_f(a.y);
            h1[4*k0+2] = gelu_f(a.z); h1[4*k0+3] = gelu_f(a.w);
        }
    }

    float h2[EMB];
    {
        const float4* sw = (const float4*)s_w2;
        const float4* sb = (const float4*)s_b2;
#pragma unroll
        for (int k0 = 0; k0 < EMB / 4; ++k0) {
            float4 a = sb[k0];
#pragma unroll
            for (int d = 0; d < EMB; ++d) {
                float4 w = sw[d * (EMB / 4) + k0];
                a.x = fmaf(h1[d], w.x, a.x);
                a.y = fmaf(h1[d], w.y, a.y);
                a.z = fmaf(h1[d], w.z, a.z);
                a.w = fmaf(h1[d], w.w, a.w);
            }
            h2[4*k0+0] = gelu_f(a.x); h2[4*k0+1] = gelu_f(a.y);
            h2[4*k0+2] = gelu_f(a.z); h2[4*k0+3] = gelu_f(a.w);
        }
    }

    // LayerNorm
    float mu = 0.0f;
#pragma unroll
    for (int k = 0; k < EMB; ++k) mu += h2[k];
    mu *= (1.0f / EMB);
    float var = 0.0f;
#pragma unroll
    for (int k = 0; k < EMB; ++k) { float t = h2[k] - mu; var = fmaf(t, t, var); }
    var *= (1.0f / EMB);
    float inv = 1.0f / sqrtf(var + 1e-5f);

    float4* ho = (float4*)(h_out + (size_t)b * EMB);
#pragma unroll
    for (int k0 = 0; k0 < EMB / 4; ++k0) {
        float4 o;
        o.x = (h2[4*k0+0] - mu) * inv * s_gam[4*k0+0] + s_bet[4*k0+0];
        o.y = (h2[4*k0+1] - mu) * inv * s_gam[4*k0+1] + s_bet[4*k0+1];
        o.z = (h2[4*k0+2] - mu) * inv * s_gam[4*k0+2] + s_bet[4*k0+2];
        o.w = (h2[4*k0+3] - mu) * inv * s_gam[4*k0+3] + s_bet[4*k0+3];
        ho[k0] = o;
    }
}

// ---------------- gate: g[e] = sum_r hU[e][r]*uV[e][r] + gb; softmax; top-2 ----------------
__global__ __launch_bounds__(256) void k_gate(
    const float* __restrict__ h, const int* __restrict__ uid,
    const float* __restrict__ gU, const float* __restrict__ uv,
    const float* __restrict__ gb,
    int* __restrict__ top_e, float* __restrict__ top_w, int* __restrict__ hist)
{
    __shared__ __align__(16) float s_gU[NE * EMB * RANK];   // 32 KB
    __shared__ __align__(16) float s_gb[NE];
    const int tid = threadIdx.x;
    for (int i = tid; i < NE * EMB * RANK; i += 256) s_gU[i] = gU[i];
    if (tid < NE) s_gb[tid] = gb[tid];
    __syncthreads();

    const int b = blockIdx.x * 256 + tid;

    float hreg[EMB];
    const float4* hp = (const float4*)(h + (size_t)b * EMB);
#pragma unroll
    for (int t = 0; t < EMB / 4; ++t) {
        float4 v = hp[t];
        hreg[4*t+0] = v.x; hreg[4*t+1] = v.y; hreg[4*t+2] = v.z; hreg[4*t+3] = v.w;
    }

    const int u = uid[b];
    const float4* sgu = (const float4*)s_gU;

    float g[NE];
#pragma unroll
    for (int e = 0; e < NE; ++e) {
        float4 a0 = make_float4(0.f, 0.f, 0.f, 0.f);
        float4 a1 = make_float4(0.f, 0.f, 0.f, 0.f);
#pragma unroll
        for (int d = 0; d < EMB; ++d) {
            float hd = hreg[d];
            float4 w0 = sgu[(e * EMB + d) * 2 + 0];
            float4 w1 = sgu[(e * EMB + d) * 2 + 1];
            a0.x = fmaf(hd, w0.x, a0.x); a0.y = fmaf(hd, w0.y, a0.y);
            a0.z = fmaf(hd, w0.z, a0.z); a0.w = fmaf(hd, w0.w, a0.w);
            a1.x = fmaf(hd, w1.x, a1.x); a1.y = fmaf(hd, w1.y, a1.y);
            a1.z = fmaf(hd, w1.z, a1.z); a1.w = fmaf(hd, w1.w, a1.w);
        }
        const float4* uvp = (const float4*)(uv + ((size_t)u * NE + e) * RANK);
        float4 v0 = uvp[0], v1 = uvp[1];
        float acc = 0.0f;
        acc = fmaf(a0.x, v0.x, acc); acc = fmaf(a0.y, v0.y, acc);
        acc = fmaf(a0.z, v0.z, acc); acc = fmaf(a0.w, v0.w, acc);
        acc = fmaf(a1.x, v1.x, acc); acc = fmaf(a1.y, v1.y, acc);
        acc = fmaf(a1.z, v1.z, acc); acc = fmaf(a1.w, v1.w, acc);
        g[e] = acc + s_gb[e];
    }

    // softmax (stable)
    float m = g[0];
#pragma unroll
    for (int e = 1; e < NE; ++e) m = fmaxf(m, g[e]);
    float w[NE];
    float s = 0.0f;
#pragma unroll
    for (int e = 0; e < NE; ++e) { w[e] = expf(g[e] - m); s += w[e]; }
    float sinv = 1.0f / s;
#pragma unroll
    for (int e = 0; e < NE; ++e) w[e] *= sinv;

    // top-2, first (lowest) index wins ties — matches lax.top_k
    int i0 = 0; float b0 = w[0];
#pragma unroll
    for (int e = 1; e < NE; ++e) { if (w[e] > b0) { b0 = w[e]; i0 = e; } }
    int i1 = (i0 == 0) ? 1 : 0; float b1v = w[i1];
#pragma unroll
    for (int e = 0; e < NE; ++e) {
        if (e != i0 && w[e] > b1v) { b1v = w[e]; i1 = e; }
    }
    float denom = fmaxf(b0 + b1v, 1e-9f);
    float w0n = b0 / denom, w1n = b1v / denom;

    top_e[2*b+0] = i0; top_w[2*b+0] = w0n;
    top_e[2*b+1] = i1; top_w[2*b+1] = w1n;
    atomicAdd(&hist[i0], 1);
    atomicAdd(&hist[i1], 1);
}

// ---------------- tiny exclusive scan over 16 bins ----------------
__global__ void k_scan(const int* __restrict__ hist, int* __restrict__ offs, int* __restrict__ cur)
{
    if (blockIdx.x == 0 && threadIdx.x == 0) {
        int acc = 0;
        for (int e = 0; e < NE; ++e) { offs[e] = acc; cur[e] = acc; acc += hist[e]; }
    }
}

// ---------------- scatter (sample, weight) pairs into expert buckets ----------------
__global__ __launch_bounds__(256) void k_scatter(
    const int* __restrict__ top_e, const float* __restrict__ top_w,
    int* __restrict__ cur, int* __restrict__ pair_b, float* __restrict__ pair_w)
{
    const int b = blockIdx.x * 256 + threadIdx.x;
#pragma unroll
    for (int sslot = 0; sslot < 2; ++sslot) {
        int e = top_e[2*b + sslot];
        int pos = atomicAdd(&cur[e], 1);
        pair_b[pos] = b;
        pair_w[pos] = top_w[2*b + sslot];
    }
}

// ---------------- expert compute: fc1+gelu, LN, fc2; out += w * lpe ----------------
__global__ __launch_bounds__(256) void k_expert(
    const float* __restrict__ h,
    const int* __restrict__ pair_b, const float* __restrict__ pair_w,
    const int* __restrict__ hist, const int* __restrict__ offs,
    const float* __restrict__ ew1, const float* __restrict__ eb1,
    const float* __restrict__ eg, const float* __restrict__ ebeta,
    const float* __restrict__ ew2, const float* __restrict__ eb2,
    float* __restrict__ out)
{
    const int e = blockIdx.y;
    const int cnt = hist[e];
    if ((int)(blockIdx.x * 256) >= cnt) return;

    __shared__ __align__(16) float s_w1[EMB * EMB];       // 16 KB
    __shared__ __align__(16) float s_w2p[EMB * W2P];      // 3 KB (padded rows)
    __shared__ __align__(16) float s_b1[EMB];
    __shared__ __align__(16) float s_g[EMB];
    __shared__ __align__(16) float s_be[EMB];
    __shared__ __align__(16) float s_b2p[W2P];

    const int tid = threadIdx.x;
    for (int i = tid; i < EMB * EMB; i += 256) s_w1[i] = ew1[(size_t)e * EMB * EMB + i];
    for (int i = tid; i < EMB * W2P; i += 256) {
        int k = i / W2P, c = i - k * W2P;
        s_w2p[i] = (c < NCLS) ? ew2[((size_t)e * EMB + k) * NCLS + c] : 0.0f;
    }
    if (tid < EMB) { s_b1[tid] = eb1[e * EMB + tid]; s_g[tid] = eg[e * EMB + tid]; s_be[tid] = ebeta[e * EMB + tid]; }
    if (tid < W2P) s_b2p[tid] = (tid < NCLS) ? eb2[e * NCLS + tid] : 0.0f;
    __syncthreads();

    const int lane = blockIdx.x * 256 + tid;
    if (lane >= cnt) return;
    const int idx = offs[e] + lane;
    const int b = pair_b[idx];
    const float pw = pair_w[idx];

    float hreg[EMB];
    const float4* hp = (const float4*)(h + (size_t)b * EMB);
#pragma unroll
    for (int t = 0; t < EMB / 4; ++t) {
        float4 v = hp[t];
        hreg[4*t+0] = v.x; hreg[4*t+1] = v.y; hreg[4*t+2] = v.z; hreg[4*t+3] = v.w;
    }

    float z[EMB];
    {
        const float4* sw = (const float4*)s_w1;
        const float4* sb = (const float4*)s_b1;
#pragma unroll
        for (int k0 = 0; k0 < EMB / 4; ++k0) {
            float4 a = sb[k0];
#pragma unroll
            for (int d = 0; d < EMB; ++d) {
                float4 w = sw[d * (EMB / 4) + k0];
                a.x = fmaf(hreg[d], w.x, a.x);
                a.y = fmaf(hreg[d], w.y, a.y);
                a.z = fmaf(hreg[d], w.z, a.z);
                a.w = fmaf(hreg[d], w.w, a.w);
            }
            z[4*k0+0] = gelu_f(a.x); z[4*k0+1] = gelu_f(a.y);
            z[4*k0+2] = gelu_f(a.z); z[4*k0+3] = gelu_f(a.w);
        }
    }

    // LayerNorm
    float mu = 0.0f;
#pragma unroll
    for (int k = 0; k < EMB; ++k) mu += z[k];
    mu *= (1.0f / EMB);
    float var = 0.0f;
#pragma unroll
    for (int k = 0; k < EMB; ++k) { float t = z[k] - mu; var = fmaf(t, t, var); }
    var *= (1.0f / EMB);
    float inv = 1.0f / sqrtf(var + 1e-5f);
#pragma unroll
    for (int k = 0; k < EMB; ++k) z[k] = (z[k] - mu) * inv * s_g[k] + s_be[k];

    // fc2 (64 -> 10), padded to 12
    float a[W2P];
#pragma unroll
    for (int c = 0; c < W2P; ++c) a[c] = s_b2p[c];
    const float4* sw2 = (const float4*)s_w2p;
#pragma unroll
    for (int k = 0; k < EMB; ++k) {
        float zk = z[k];
        float4 w0 = sw2[k * 3 + 0];
        float4 w1 = sw2[k * 3 + 1];
        float4 w2 = sw2[k * 3 + 2];
        a[0] = fmaf(zk, w0.x, a[0]); a[1] = fmaf(zk, w0.y, a[1]);
        a[2] = fmaf(zk, w0.z, a[2]); a[3] = fmaf(zk, w0.w, a[3]);
        a[4] = fmaf(zk, w1.x, a[4]); a[5] = fmaf(zk, w1.y, a[5]);
        a[6] = fmaf(zk, w1.z, a[6]); a[7] = fmaf(zk, w1.w, a[7]);
        a[8] = fmaf(zk, w2.x, a[8]); a[9] = fmaf(zk, w2.y, a[9]);
    }
#pragma unroll
    for (int c = 0; c < NCLS; ++c)
        atomicAdd(out + (size_t)b * NCLS + c, pw * a[c]);
}

extern "C" void kernel_launch(void* const* d_in, const int* in_sizes, int n_in,
                              void* d_out, int out_size, void* d_ws, size_t ws_size,
                              hipStream_t stream)
{
    (void)in_sizes; (void)n_in; (void)out_size; (void)ws_size;

    const float* x     = (const float*)d_in[0];
    const int*   uid   = (const int*)  d_in[1];
    const float* bb_w1 = (const float*)d_in[2];
    const float* bb_b1 = (const float*)d_in[3];
    const float* bb_w2 = (const float*)d_in[4];
    const float* bb_b2 = (const float*)d_in[5];
    const float* bb_g  = (const float*)d_in[6];
    const float* bb_be = (const float*)d_in[7];
    const float* gU    = (const float*)d_in[8];
    const float* gV    = (const float*)d_in[9];
    const float* gb    = (const float*)d_in[10];
    const float* e_w1  = (const float*)d_in[11];
    const float* e_b1  = (const float*)d_in[12];
    const float* e_g   = (const float*)d_in[13];
    const float* e_be  = (const float*)d_in[14];
    const float* e_w2  = (const float*)d_in[15];
    const float* e_b2  = (const float*)d_in[16];
    const float* ut    = (const float*)d_in[17];

    float* out = (float*)d_out;
    char*  ws  = (char*)d_ws;

    float* h      = (float*)(ws + OFF_H);
    int*   top_e  = (int*)  (ws + OFF_TOPE);
    float* top_w  = (float*)(ws + OFF_TOPW);
    int*   pair_b = (int*)  (ws + OFF_PAIRB);
    float* pair_w = (float*)(ws + OFF_PAIRW);
    float* uv     = (float*)(ws + OFF_UV);
    int*   hist   = (int*)  (ws + OFF_HIST);
    int*   offs   = (int*)  (ws + OFF_OFFS);
    int*   cur    = (int*)  (ws + OFF_CUR);

    hipMemsetAsync(out, 0, (size_t)BATCH * NCLS * sizeof(float), stream);
    hipMemsetAsync(hist, 0, NE * sizeof(int), stream);

    k_uv<<<(NUSERS * NE + 255) / 256, 256, 0, stream>>>(gV, ut, uv);
    k_backbone<<<BATCH / 256, 256, 0, stream>>>(x, bb_w1, bb_b1, bb_w2, bb_b2, bb_g, bb_be, h);
    k_gate<<<BATCH / 256, 256, 0, stream>>>(h, uid, gU, uv, gb, top_e, top_w, hist);
    k_scan<<<1, 64, 0, stream>>>(hist, offs, cur);
    k_scatter<<<BATCH / 256, 256, 0, stream>>>(top_e, top_w, cur, pair_b, pair_w);
    dim3 eg(1024, NE);
    k_expert<<<eg, 256, 0, stream>>>(h, pair_b, pair_w, hist, offs,
                                     e_w1, e_b1, e_g, e_be, e_w2, e_b2, out);
}